// Round 7
// baseline (279.178 us; speedup 1.0000x reference)
//
#include <hip/hip_runtime.h>

// Shapes fixed by the reference.
#define N_  64
#define T_  4096
#define D_  128
#define CH_ 32            // t-chunks per n
#define TC_ (T_ / CH_)    // 128 t per chunk

// ---------------------------------------------------------------------------
// Fused per-chunk flash pass. Block (n,c), 256 threads (4 waves).
// KEY CHANGE vs round 1 (VGPR=24, latency-bound, 1.4 TB/s):
//   * ALL 16 K-row float4 loads issued into registers BEFORE the dependent
//     shfl reduce chains (16 KB in flight per wave instead of ~2).
//   * ALL 16 V-row loads issued BEFORE the softmax barriers, so their HBM
//     latency hides under the max/sum reduction (async-stage idiom).
// Wave layout: half-wave 0 (lanes 0-31) covers row t, half-wave 1 row t+1;
// one wave load = 1KB across two rows; 5-shfl half-wave dot reduce.
// ---------------------------------------------------------------------------
__global__ __launch_bounds__(256) void chunk_kernel(
    const float* __restrict__ key, const float* __restrict__ value,
    const float* __restrict__ query, const int* __restrict__ slen,
    float* __restrict__ mask_out, float* __restrict__ m_ws,
    float* __restrict__ s_ws, float* __restrict__ acc_ws)
{
    const int n    = blockIdx.x / CH_;
    const int c    = blockIdx.x % CH_;
    const int tid  = threadIdx.x;
    const int lane = tid & 63;
    const int wv   = tid >> 6;        // 0..3
    const int half = lane >> 5;       // 0 or 1 (which t of the pair)
    const int hl   = lane & 31;       // lane within half-wave
    const int tbase = c * TC_;
    const int len   = slen[n];

    __shared__ float  ep[TC_];        // p values
    __shared__ float  wred[8];
    __shared__ float4 red[4][32];

    const float4 q4 = *reinterpret_cast<const float4*>(query + n * D_ + hl * 4);

    // Per-wave base row: t = tbase + wv*32 + half, advancing 2 t per step.
    const size_t rowstride2 = (size_t)2 * N_ * D_;           // 2 t's, in floats
    const float* krow = key   + ((size_t)(tbase + wv * 32 + half) * N_ + n) * D_ + hl * 4;
    const float* vrow = value + ((size_t)(tbase + wv * 32 + half) * N_ + n) * D_ + hl * 4;

    // ---- phase 1a: issue ALL 16 K loads (independent, 16 KB/wave in flight) ----
    float4 kbuf[16];
    #pragma unroll
    for (int i = 0; i < 16; ++i)
        kbuf[i] = *reinterpret_cast<const float4*>(krow + (size_t)i * rowstride2);

    // ---- phase 1b: 16 independent dot+reduce chains ----
    #pragma unroll
    for (int i = 0; i < 16; ++i) {
        float p = kbuf[i].x * q4.x + kbuf[i].y * q4.y
                + kbuf[i].z * q4.z + kbuf[i].w * q4.w;
        #pragma unroll
        for (int off = 16; off; off >>= 1) p += __shfl_xor(p, off, 64);
        const int lt = wv * 32 + i * 2 + half;
        if (hl == 0) ep[lt] = (tbase + lt < len) ? p : 0.f;  // multiplicative mask
    }

    // ---- issue ALL 16 V loads now; latency hides under softmax below ----
    float4 vbuf[16];
    #pragma unroll
    for (int i = 0; i < 16; ++i)
        vbuf[i] = *reinterpret_cast<const float4*>(vrow + (size_t)i * rowstride2);

    __syncthreads();                   // publishes ep[] (raw masked energies)

    // ---- chunk max ----
    const float ev = (tid < TC_) ? ep[tid] : -3.4e38f;
    float m = ev;
    #pragma unroll
    for (int off = 32; off; off >>= 1) m = fmaxf(m, __shfl_xor(m, off, 64));
    if (lane == 0) wred[wv] = m;
    __syncthreads();
    m = fmaxf(fmaxf(wred[0], wred[1]), fmaxf(wred[2], wred[3]));

    // ---- p = exp(e - m), chunk sum; also emit mask output ----
    float sp = 0.f;
    if (tid < TC_) {
        const float p = __expf(ev - m);
        ep[tid] = p;                   // own slot; published by barrier below
        sp = p;
        mask_out[n * T_ + tbase + tid] = (tbase + tid < len) ? 1.f : 0.f;
    }
    #pragma unroll
    for (int off = 32; off; off >>= 1) sp += __shfl_xor(sp, off, 64);
    if (lane == 0) wred[4 + wv] = sp;
    __syncthreads();                   // publishes ep[] (p values) and wred[4..7]
    if (tid == 0) {
        m_ws[n * CH_ + c] = m;
        s_ws[n * CH_ + c] = wred[4] + wred[5] + wred[6] + wred[7];
    }

    // ---- phase 2: weighted V accumulation from registers ----
    float4 acc = make_float4(0.f, 0.f, 0.f, 0.f);
    #pragma unroll
    for (int i = 0; i < 16; ++i) {
        const float pv = ep[wv * 32 + i * 2 + half];   // 2-way broadcast, free
        acc.x += pv * vbuf[i].x; acc.y += pv * vbuf[i].y;
        acc.z += pv * vbuf[i].z; acc.w += pv * vbuf[i].w;
    }
    // combine the two halves (both hold the same d-range, adjacent t's)
    acc.x += __shfl_xor(acc.x, 32, 64);
    acc.y += __shfl_xor(acc.y, 32, 64);
    acc.z += __shfl_xor(acc.z, 32, 64);
    acc.w += __shfl_xor(acc.w, 32, 64);
    if (half == 0) red[wv][hl] = acc;
    __syncthreads();
    if (tid < 32) {
        const float4 a = red[0][tid], b = red[1][tid];
        const float4 e = red[2][tid], d = red[3][tid];
        float4 r;
        r.x = (a.x + b.x) + (e.x + d.x);
        r.y = (a.y + b.y) + (e.y + d.y);
        r.z = (a.z + b.z) + (e.z + d.z);
        r.w = (a.w + b.w) + (e.w + d.w);
        *reinterpret_cast<float4*>(acc_ws + ((size_t)(n * CH_ + c)) * D_ + tid * 4) = r;
    }
}

// ---------------------------------------------------------------------------
// Combine 32 chunk partials per n.
//   M = max_c m_c;  S = sum_c s_c*exp(m_c-M);  ctx = sum_c exp(m_c-M)*acc_c / S
// ---------------------------------------------------------------------------
__global__ __launch_bounds__(64) void finalize_kernel(
    const float* __restrict__ m_ws, const float* __restrict__ s_ws,
    const float* __restrict__ acc_ws, float* __restrict__ ctx)
{
    const int n    = blockIdx.x;
    const int lane = threadIdx.x;

    const float mc = (lane < CH_) ? m_ws[n * CH_ + lane] : -3.4e38f;
    float M = mc;
    #pragma unroll
    for (int off = 32; off; off >>= 1) M = fmaxf(M, __shfl_xor(M, off, 64));

    const float ew = (lane < CH_) ? __expf(mc - M) : 0.f;
    float S = (lane < CH_) ? s_ws[n * CH_ + lane] * ew : 0.f;
    #pragma unroll
    for (int off = 32; off; off >>= 1) S += __shfl_xor(S, off, 64);

    float2 r = make_float2(0.f, 0.f);
    #pragma unroll 8
    for (int c = 0; c < CH_; ++c) {
        const float w = __shfl(ew, c, 64);   // broadcast chunk c's weight
        const float2 a = *reinterpret_cast<const float2*>(
            acc_ws + ((size_t)(n * CH_ + c)) * D_ + lane * 2);
        r.x += w * a.x; r.y += w * a.y;
    }
    const float invS = 1.f / S;
    *reinterpret_cast<float2*>(ctx + n * D_ + lane * 2) =
        make_float2(r.x * invS, r.y * invS);
}

// ---------------------------------------------------------------------------
extern "C" void kernel_launch(void* const* d_in, const int* in_sizes, int n_in,
                              void* d_out, int out_size, void* d_ws, size_t ws_size,
                              hipStream_t stream) {
    const float* query = (const float*)d_in[0];   // (N, D)
    const float* key   = (const float*)d_in[1];   // (T, N, D)
    const float* value = (const float*)d_in[2];   // (T, N, D)
    const int*   slen  = (const int*)d_in[3];     // (N,)

    float* out      = (float*)d_out;
    float* ctx_out  = out;                // N*D floats
    float* mask_out = out + N_ * D_;      // N*T floats

    float* m_ws   = (float*)d_ws;                 // N*CH
    float* s_ws   = m_ws + N_ * CH_;              // N*CH
    float* acc_ws = s_ws + N_ * CH_;              // N*CH*D

    chunk_kernel<<<N_ * CH_, 256, 0, stream>>>(key, value, query, slen,
                                               mask_out, m_ws, s_ws, acc_ws);
    finalize_kernel<<<N_, 64, 0, stream>>>(m_ws, s_ws, acc_ws, ctx_out);
}